// Round 10
// baseline (295.037 us; speedup 1.0000x reference)
//
#include <hip/hip_runtime.h>
#include <hip/hip_bf16.h>

#define NT 16384   // tokens
#define DM 4096    // d_model
#define NE 64      // experts
#define MB 32      // tokens per block
#define KG 4       // k-split across wave pairs
#define KSW (DM / KG)    // 1024 k per wave
#define KST (KSW / 32)   // 32 mfma ksteps per wave

typedef __attribute__((ext_vector_type(8))) short bf16x8;   // 8 bf16 = 4 VGPRs
typedef __attribute__((ext_vector_type(4))) float f32x4;

__device__ __forceinline__ unsigned short bf16_rne(float f) {
  const unsigned u = __float_as_uint(f);
  return (unsigned short)((u + 0x7FFFu + ((u >> 16) & 1u)) >> 16);
}

// hi/lo split of a float pair via packed HW cvt (validated R7-R9 class)
__device__ __forceinline__ void split2(float fa, float fb, unsigned& hp, unsigned& lp) {
  union { __hip_bfloat162 h; unsigned u; } cv;
  cv.h = __float22bfloat162_rn(make_float2(fa, fb));
  hp = cv.u;
  const float ha = __uint_as_float(hp << 16);
  const float hb = __uint_as_float(hp & 0xFFFF0000u);
  cv.h = __float22bfloat162_rn(make_float2(fa - ha, fb - hb));
  lp = cv.u;
}

__device__ __forceinline__ void splitA(const float4& c0, const float4& c1,
                                       bf16x8& hi, bf16x8& lo) {
  union { unsigned u[4]; bf16x8 v; } H, L;
  split2(c0.x, c0.y, H.u[0], L.u[0]);
  split2(c0.z, c0.w, H.u[1], L.u[1]);
  split2(c1.x, c1.y, H.u[2], L.u[2]);
  split2(c1.z, c1.w, H.u[3], L.u[3]);
  hi = H.v; lo = L.v;
}

// W pre-pass (validated, unchanged): fp32 -> split bf16 hi/lo in exact MFMA
// B-fragment order. id = ks*256 + nt*64 + lane;
// elem j = W[e=nt*16+(lane&15)][k=ks*32+(lane>>4)*8+j]. Idempotent.
__global__ void w_convert(const float* __restrict__ W,
                          unsigned short* __restrict__ Whi,
                          unsigned short* __restrict__ Wlo) {
  const int id   = blockIdx.x * 256 + threadIdx.x;  // 0..32767
  const int lane = id & 63;
  const int nt   = (id >> 6) & 3;
  const int ks   = id >> 8;                         // 0..127
  const float* src = W + (size_t)(nt * 16 + (lane & 15)) * DM + ks * 32 + (lane >> 4) * 8;
  unsigned short h[8], l[8];
#pragma unroll
  for (int j = 0; j < 8; ++j) {
    const float f = src[j];
    h[j] = bf16_rne(f);
    l[j] = bf16_rne(f - __uint_as_float((unsigned)h[j] << 16));
  }
  uint4 ph, pl;
  ph.x = h[0] | ((unsigned)h[1] << 16); ph.y = h[2] | ((unsigned)h[3] << 16);
  ph.z = h[4] | ((unsigned)h[5] << 16); ph.w = h[6] | ((unsigned)h[7] << 16);
  pl.x = l[0] | ((unsigned)l[1] << 16); pl.y = l[2] | ((unsigned)l[3] << 16);
  pl.z = l[4] | ((unsigned)l[5] << 16); pl.w = l[6] | ((unsigned)l[7] << 16);
  *(uint4*)(Whi + (size_t)id * 8) = ph;
  *(uint4*)(Wlo + (size_t)id * 8) = pl;
}

// ---- register-set pipeline macros (statically named sets; rule #20) ----
#define LDA(s, idx) {                                            \
    const int _o = (idx) * 32;                                   \
    s##a = *(const float4*)(a0p + _o);                           \
    s##b = *(const float4*)(a0p + _o + 4);                       \
    s##c = *(const float4*)(a1p + _o);                           \
    s##d = *(const float4*)(a1p + _o + 4); }

#define LDB(s, idx) {                                            \
    const size_t _o = (size_t)(idx) * 2048;                      \
    s##h0 = *(const bf16x8*)(bhp + _o);                          \
    s##h1 = *(const bf16x8*)(bhp + _o + 512);                    \
    s##l0 = *(const bf16x8*)(blp + _o);                          \
    s##l1 = *(const bf16x8*)(blp + _o + 512); }

#define CMP(sa, sb) {                                                                  \
    bf16x8 ah0, al0, ah1, al1;                                                         \
    splitA(sa##a, sa##b, ah0, al0);                                                    \
    splitA(sa##c, sa##d, ah1, al1);                                                    \
    acc00 = __builtin_amdgcn_mfma_f32_16x16x32_bf16(al0, sb##l0, acc00, 0, 0, 0);      \
    acc00 = __builtin_amdgcn_mfma_f32_16x16x32_bf16(al0, sb##h0, acc00, 0, 0, 0);      \
    acc00 = __builtin_amdgcn_mfma_f32_16x16x32_bf16(ah0, sb##l0, acc00, 0, 0, 0);      \
    acc00 = __builtin_amdgcn_mfma_f32_16x16x32_bf16(ah0, sb##h0, acc00, 0, 0, 0);      \
    acc01 = __builtin_amdgcn_mfma_f32_16x16x32_bf16(al0, sb##l1, acc01, 0, 0, 0);      \
    acc01 = __builtin_amdgcn_mfma_f32_16x16x32_bf16(al0, sb##h1, acc01, 0, 0, 0);      \
    acc01 = __builtin_amdgcn_mfma_f32_16x16x32_bf16(ah0, sb##l1, acc01, 0, 0, 0);      \
    acc01 = __builtin_amdgcn_mfma_f32_16x16x32_bf16(ah0, sb##h1, acc01, 0, 0, 0);      \
    acc10 = __builtin_amdgcn_mfma_f32_16x16x32_bf16(al1, sb##l0, acc10, 0, 0, 0);      \
    acc10 = __builtin_amdgcn_mfma_f32_16x16x32_bf16(al1, sb##h0, acc10, 0, 0, 0);      \
    acc10 = __builtin_amdgcn_mfma_f32_16x16x32_bf16(ah1, sb##l0, acc10, 0, 0, 0);      \
    acc10 = __builtin_amdgcn_mfma_f32_16x16x32_bf16(ah1, sb##h0, acc10, 0, 0, 0);      \
    acc11 = __builtin_amdgcn_mfma_f32_16x16x32_bf16(al1, sb##l1, acc11, 0, 0, 0);      \
    acc11 = __builtin_amdgcn_mfma_f32_16x16x32_bf16(al1, sb##h1, acc11, 0, 0, 0);      \
    acc11 = __builtin_amdgcn_mfma_f32_16x16x32_bf16(ah1, sb##l1, acc11, 0, 0, 0);      \
    acc11 = __builtin_amdgcn_mfma_f32_16x16x32_bf16(ah1, sb##h1, acc11, 0, 0, 0); }

// Main: block = 512 thr = 8 waves; wave (eg=wv&1, kg=wv>>1) owns
// 32 tokens x experts [32eg,32eg+32) x k-slice [kg*1024,(kg+1)*1024).
// Fully per-wave-independent K loop: NO LDS, NO barriers -> compiler emits
// counted vmcnt (no vmcnt(0) drain). A 3-deep + B 2-deep register pipeline,
// 4-pass split-bf16 mfma (validated numerics). k-combine via LDS slabs after
// the loop; validated epilogue fused.
__launch_bounds__(512, 4)
__global__ void moe_mfma(const float* __restrict__ x,
                         const unsigned short* __restrict__ Whi,
                         const unsigned short* __restrict__ Wlo,
                         float* __restrict__ out,
                         float* __restrict__ bsum) {
  __shared__ float lg[KG][MB][NE + 2];   // 33.8 KiB
  __shared__ float esums[8][NE];         // 2 KiB

  const int tid  = threadIdx.x;
  const int lane = tid & 63;
  const int wvu  = __builtin_amdgcn_readfirstlane(tid >> 6);
  const int eg   = wvu & 1;     // expert half
  const int kg   = wvu >> 1;    // k-split group 0..3
  const int blk  = blockIdx.x;
  const int tok0 = blk * MB;

  // A: row = tok0 + 16*mt + (lane&15), cols kg*1024 + i*32 + (lane>>4)*8 + j
  const float* a0p = x + (size_t)(tok0 + (lane & 15)) * DM + kg * KSW + (lane >> 4) * 8;
  const float* a1p = a0p + (size_t)16 * DM;
  // B frag base: shorts offset = ks*2048 + nt*512 + lane*8, ks = kg*KST + i, nt = 2eg+{0,1}
  const unsigned short* bhp = Whi + (size_t)(kg * KST) * 2048 + (size_t)(2 * eg) * 512 + lane * 8;
  const unsigned short* blp = Wlo + (size_t)(kg * KST) * 2048 + (size_t)(2 * eg) * 512 + lane * 8;

  f32x4 acc00 = (f32x4){0.f, 0.f, 0.f, 0.f};
  f32x4 acc01 = (f32x4){0.f, 0.f, 0.f, 0.f};
  f32x4 acc10 = (f32x4){0.f, 0.f, 0.f, 0.f};
  f32x4 acc11 = (f32x4){0.f, 0.f, 0.f, 0.f};

  float4 A0a, A0b, A0c, A0d, A1a, A1b, A1c, A1d, A2a, A2b, A2c, A2d;
  bf16x8 B0h0, B0h1, B0l0, B0l1, B1h0, B1h1, B1l0, B1l1;

  // prologue: A 3-deep, B 2-deep
  LDA(A0, 0); LDA(A1, 1); LDA(A2, 2);
  LDB(B0, 0); LDB(B1, 1);

  // period-6 rotation (A period 3, B period 2), 5 iters = ksteps 0..29
  for (int i = 0; i < 30; i += 6) {
    CMP(A0, B0); LDA(A0, i + 3);          LDB(B0, i + 2);
    CMP(A1, B1); LDA(A1, i + 4);          LDB(B1, i + 3);
    CMP(A2, B0); LDA(A2, i + 5);          LDB(B0, i + 4);
    CMP(A0, B1); LDA(A0, i + 6);          LDB(B1, i + 5);
    CMP(A1, B0); LDA(A1, min(i + 7, 31)); LDB(B0, i + 6);
    CMP(A2, B1); LDA(A2, min(i + 8, 31)); LDB(B1, min(i + 7, 31));
  }
  CMP(A0, B0);   // kstep 30
  CMP(A1, B1);   // kstep 31

  // ---- k-split combine via LDS slabs (disjoint [kg][*][32eg..32eg+31]) ----
  // D layout (m89, validated): token = 16mt + (lane>>4)*4 + r, expert = 32eg + 16ntl + (lane&15)
#pragma unroll
  for (int r = 0; r < 4; ++r) {
    const int tr = (lane >> 4) * 4 + r;
    lg[kg][tr][eg * 32 + (lane & 15)]           = acc00[r];
    lg[kg][tr][eg * 32 + 16 + (lane & 15)]      = acc01[r];
    lg[kg][16 + tr][eg * 32 + (lane & 15)]      = acc10[r];
    lg[kg][16 + tr][eg * 32 + 16 + (lane & 15)] = acc11[r];
  }
  __syncthreads();

  // ---- epilogue (validated): wave wvu owns tokens tok0 + 4wvu + {0..3} ----
  float esum = 0.f;
#pragma unroll
  for (int ti = 0; ti < 4; ++ti) {
    const int t = 4 * wvu + ti;
    const float lgv = lg[0][t][lane] + lg[1][t][lane] + lg[2][t][lane] + lg[3][t][lane];

    float m = lgv;
#pragma unroll
    for (int off = 32; off; off >>= 1) m = fmaxf(m, __shfl_xor(m, off, 64));
    const float p = __expf(lgv - m);
    float Z = p;
#pragma unroll
    for (int off = 32; off; off >>= 1) Z += __shfl_xor(Z, off, 64);
    const float s = p / Z;
    esum += s;

    // top-1 (value desc, index asc — matches lax.top_k tie-break)
    float v1 = s; int i1 = lane;
#pragma unroll
    for (int off = 32; off; off >>= 1) {
      const float ov = __shfl_xor(v1, off, 64);
      const int   oi = __shfl_xor(i1, off, 64);
      if (ov > v1 || (ov == v1 && oi < i1)) { v1 = ov; i1 = oi; }
    }
    // top-2: mask winner (scores >= 0, so -1 acts as -inf)
    float sv = (lane == i1) ? -1.f : s;
    float v2 = sv; int i2 = lane;
#pragma unroll
    for (int off = 32; off; off >>= 1) {
      const float ov = __shfl_xor(v2, off, 64);
      const int   oi = __shfl_xor(i2, off, 64);
      if (ov > v2 || (ov == v2 && oi < i2)) { v2 = ov; i2 = oi; }
    }

    if (lane == 0) {
      const int gt = tok0 + t;
      const float inv = 1.f / (v1 + v2);
      out[2 * gt]              = v1 * inv;
      out[2 * gt + 1]          = v2 * inv;
      out[2 * NT + 2 * gt]     = (float)i1;
      out[2 * NT + 2 * gt + 1] = (float)i2;
    }
  }

  // per-block expert score sums (deterministic tree reduce, no atomics)
  esums[wvu][lane] = esum;
  __syncthreads();
  if (wvu == 0) {
    float tot = 0.f;
#pragma unroll
    for (int w = 0; w < 8; ++w) tot += esums[w][lane];
    bsum[blk * NE + lane] = tot;
  }
}

// Reduce NT/MB per-block expert sums -> load balancing loss
__global__ void moe_gate_loss(const float* __restrict__ bsum,
                              float* __restrict__ out) {
  __shared__ float red[4][64];
  const int e = threadIdx.x & 63;
  const int g = threadIdx.x >> 6;
  float s = 0.f;
  for (int b = g; b < NT / MB; b += 4) s += bsum[b * 64 + e];
  red[g][e] = s;
  __syncthreads();
  if (threadIdx.x < 64) {
    const float tot = red[0][e] + red[1][e] + red[2][e] + red[3][e];
    const float p = tot * (1.f / (float)NT);
    float term = p * logf(p + 1e-8f);
#pragma unroll
    for (int off = 32; off; off >>= 1) term += __shfl_xor(term, off, 64);
    if (e == 0) out[4 * NT] = term;  // out[65536]
  }
}

extern "C" void kernel_launch(void* const* d_in, const int* in_sizes, int n_in,
                              void* d_out, int out_size, void* d_ws, size_t ws_size,
                              hipStream_t stream) {
  const float* x = (const float*)d_in[0];   // [16384, 4096]
  const float* W = (const float*)d_in[1];   // [64, 4096]
  float* out = (float*)d_out;               // scores[32768] | idx[32768] | loss[1]

  unsigned short* Whi = (unsigned short*)d_ws;        // 512 KiB
  unsigned short* Wlo = Whi + (size_t)NE * DM;        // 512 KiB
  float* bsum = (float*)(Wlo + (size_t)NE * DM);      // [512][64]

  hipLaunchKernelGGL(w_convert, dim3(128), dim3(256), 0, stream, W, Whi, Wlo);
  hipLaunchKernelGGL(moe_mfma, dim3(NT / MB), dim3(512), 0, stream, x, Whi, Wlo, out, bsum);
  hipLaunchKernelGGL(moe_gate_loss, dim3(1), dim3(256), 0, stream, bsum, out);
}

// Round 11
// 223.422 us; speedup vs baseline: 1.3205x; 1.3205x over previous
//
#include <hip/hip_runtime.h>
#include <hip/hip_bf16.h>

#define NT 16384   // tokens
#define DM 4096    // d_model
#define NE 64      // experts
#define MB 16      // tokens per block
#define KST 128    // mfma ksteps (full K per wave)

typedef __attribute__((ext_vector_type(8))) short bf16x8;   // 8 bf16 = 4 VGPRs
typedef __attribute__((ext_vector_type(4))) float f32x4;

__device__ __forceinline__ unsigned short bf16_rne(float f) {
  const unsigned u = __float_as_uint(f);
  return (unsigned short)((u + 0x7FFFu + ((u >> 16) & 1u)) >> 16);
}

// hi/lo split of a float pair via packed HW cvt (validated R7-R10 class)
__device__ __forceinline__ void split2(float fa, float fb, unsigned& hp, unsigned& lp) {
  union { __hip_bfloat162 h; unsigned u; } cv;
  cv.h = __float22bfloat162_rn(make_float2(fa, fb));
  hp = cv.u;
  const float ha = __uint_as_float(hp << 16);
  const float hb = __uint_as_float(hp & 0xFFFF0000u);
  cv.h = __float22bfloat162_rn(make_float2(fa - ha, fb - hb));
  lp = cv.u;
}

__device__ __forceinline__ void splitA(const float4& c0, const float4& c1,
                                       bf16x8& hi, bf16x8& lo) {
  union { unsigned u[4]; bf16x8 v; } H, L;
  split2(c0.x, c0.y, H.u[0], L.u[0]);
  split2(c0.z, c0.w, H.u[1], L.u[1]);
  split2(c1.x, c1.y, H.u[2], L.u[2]);
  split2(c1.z, c1.w, H.u[3], L.u[3]);
  hi = H.v; lo = L.v;
}

// W pre-pass (validated, unchanged): fp32 -> split bf16 hi/lo in exact MFMA
// B-fragment order. id = ks*256 + nt*64 + lane;
// elem j = W[e=nt*16+(lane&15)][k=ks*32+(lane>>4)*8+j]. Idempotent.
__global__ void w_convert(const float* __restrict__ W,
                          unsigned short* __restrict__ Whi,
                          unsigned short* __restrict__ Wlo) {
  const int id   = blockIdx.x * 256 + threadIdx.x;  // 0..32767
  const int lane = id & 63;
  const int nt   = (id >> 6) & 3;
  const int ks   = id >> 8;                         // 0..127
  const float* src = W + (size_t)(nt * 16 + (lane & 15)) * DM + ks * 32 + (lane >> 4) * 8;
  unsigned short h[8], l[8];
#pragma unroll
  for (int j = 0; j < 8; ++j) {
    const float f = src[j];
    h[j] = bf16_rne(f);
    l[j] = bf16_rne(f - __uint_as_float((unsigned)h[j] << 16));
  }
  uint4 ph, pl;
  ph.x = h[0] | ((unsigned)h[1] << 16); ph.y = h[2] | ((unsigned)h[3] << 16);
  ph.z = h[4] | ((unsigned)h[5] << 16); ph.w = h[6] | ((unsigned)h[7] << 16);
  pl.x = l[0] | ((unsigned)l[1] << 16); pl.y = l[2] | ((unsigned)l[3] << 16);
  pl.z = l[4] | ((unsigned)l[5] << 16); pl.w = l[6] | ((unsigned)l[7] << 16);
  *(uint4*)(Whi + (size_t)id * 8) = ph;
  *(uint4*)(Wlo + (size_t)id * 8) = pl;
}

// ---- minimal-footprint pipeline macros (statically named sets; rule #20) ----
#define LDA_(s, idx) {                                           \
    const int _o = (idx) * 32;                                   \
    s##a = *(const float4*)(ap + _o);                            \
    s##b = *(const float4*)(ap + _o + 4); }

#define LDB_(s, idx) {                                           \
    const size_t _o = (size_t)(idx) * 2048;                      \
    s##h = *(const bf16x8*)(bhp + _o);                           \
    s##l = *(const bf16x8*)(blp + _o); }

#define CMP_(sa, sb) {                                                             \
    bf16x8 ah, al;                                                                 \
    splitA(sa##a, sa##b, ah, al);                                                  \
    acc = __builtin_amdgcn_mfma_f32_16x16x32_bf16(al, sb##l, acc, 0, 0, 0);        \
    acc = __builtin_amdgcn_mfma_f32_16x16x32_bf16(al, sb##h, acc, 0, 0, 0);        \
    acc = __builtin_amdgcn_mfma_f32_16x16x32_bf16(ah, sb##l, acc, 0, 0, 0);        \
    acc = __builtin_amdgcn_mfma_f32_16x16x32_bf16(ah, sb##h, acc, 0, 0, 0); }

// Main: block = 256 thr = 4 waves; wave wv = 16 tokens x experts [16wv,16wv+16)
// x full K (128 ksteps). Tiny register footprint (acc=4, A/B 1-deep prefetch,
// ~70 VGPR) -> 4+ blocks/CU resident (grid 1024): wave-level TLP hides HBM/L2
// latency (m114), inter-block overlap removes ramp/epilogue bubbles.
// No LDS/barriers in K loop. 4-pass split-bf16 mfma (validated numerics).
__launch_bounds__(256, 4)
__global__ void moe_mfma(const float* __restrict__ x,
                         const unsigned short* __restrict__ Whi,
                         const unsigned short* __restrict__ Wlo,
                         float* __restrict__ out,
                         float* __restrict__ bsum) {
  __shared__ float lg[MB][NE + 2];   // 4.2 KiB
  __shared__ float esums[4][NE];     // 1 KiB

  const int tid  = threadIdx.x;
  const int lane = tid & 63;
  const int wvu  = __builtin_amdgcn_readfirstlane(tid >> 6);  // expert group 0..3
  const int blk  = blockIdx.x;
  const int tok0 = blk * MB;

  // A: row = tok0 + (lane&15), col = i*32 + (lane>>4)*8 + j  (frag layout, validated)
  const float* ap = x + (size_t)(tok0 + (lane & 15)) * DM + (lane >> 4) * 8;
  // B frag base (shorts): ks*2048 + nt*512 + lane*8, nt = wvu
  const unsigned short* bhp = Whi + (size_t)wvu * 512 + lane * 8;
  const unsigned short* blp = Wlo + (size_t)wvu * 512 + lane * 8;

  f32x4 acc = (f32x4){0.f, 0.f, 0.f, 0.f};

  float4 A0a, A0b, A1a, A1b;
  bf16x8 B0h, B0l, B1h, B1l;

  LDA_(A0, 0); LDB_(B0, 0);
  LDA_(A1, 1); LDB_(B1, 1);

  for (int i = 0; i < KST - 2; i += 2) {
    CMP_(A0, B0); LDA_(A0, i + 2); LDB_(B0, i + 2);
    CMP_(A1, B1); LDA_(A1, i + 3); LDB_(B1, i + 3);
  }
  CMP_(A0, B0);   // kstep 126
  CMP_(A1, B1);   // kstep 127

  // D layout (m89, validated): token = (lane>>4)*4 + r, expert = 16*wvu + (lane&15)
#pragma unroll
  for (int r = 0; r < 4; ++r)
    lg[(lane >> 4) * 4 + r][wvu * 16 + (lane & 15)] = acc[r];
  __syncthreads();

  // Epilogue (validated verbatim): wave wvu owns tokens tok0 + 4wvu + {0..3}.
  float esum = 0.f;
#pragma unroll
  for (int ti = 0; ti < 4; ++ti) {
    const int t = 4 * wvu + ti;
    const float lgv = lg[t][lane];

    float m = lgv;
#pragma unroll
    for (int off = 32; off; off >>= 1) m = fmaxf(m, __shfl_xor(m, off, 64));
    const float p = __expf(lgv - m);
    float Z = p;
#pragma unroll
    for (int off = 32; off; off >>= 1) Z += __shfl_xor(Z, off, 64);
    const float s = p / Z;
    esum += s;

    // top-1 (value desc, index asc — matches lax.top_k tie-break)
    float v1 = s; int i1 = lane;
#pragma unroll
    for (int off = 32; off; off >>= 1) {
      const float ov = __shfl_xor(v1, off, 64);
      const int   oi = __shfl_xor(i1, off, 64);
      if (ov > v1 || (ov == v1 && oi < i1)) { v1 = ov; i1 = oi; }
    }
    // top-2: mask winner (scores >= 0, so -1 acts as -inf)
    float sv = (lane == i1) ? -1.f : s;
    float v2 = sv; int i2 = lane;
#pragma unroll
    for (int off = 32; off; off >>= 1) {
      const float ov = __shfl_xor(v2, off, 64);
      const int   oi = __shfl_xor(i2, off, 64);
      if (ov > v2 || (ov == v2 && oi < i2)) { v2 = ov; i2 = oi; }
    }

    if (lane == 0) {
      const int gt = tok0 + t;
      const float inv = 1.f / (v1 + v2);
      out[2 * gt]              = v1 * inv;
      out[2 * gt + 1]          = v2 * inv;
      out[2 * NT + 2 * gt]     = (float)i1;
      out[2 * NT + 2 * gt + 1] = (float)i2;
    }
  }

  // per-block expert score sums (deterministic tree reduce, no atomics)
  esums[wvu][lane] = esum;
  __syncthreads();
  if (wvu == 0) {
    float tot = esums[0][lane] + esums[1][lane] + esums[2][lane] + esums[3][lane];
    bsum[blk * NE + lane] = tot;
  }
}

// Reduce NT/MB per-block expert sums -> load balancing loss
__global__ void moe_gate_loss(const float* __restrict__ bsum,
                              float* __restrict__ out) {
  __shared__ float red[4][64];
  const int e = threadIdx.x & 63;
  const int g = threadIdx.x >> 6;
  float s = 0.f;
  for (int b = g; b < NT / MB; b += 4) s += bsum[b * 64 + e];
  red[g][e] = s;
  __syncthreads();
  if (threadIdx.x < 64) {
    const float tot = red[0][e] + red[1][e] + red[2][e] + red[3][e];
    const float p = tot * (1.f / (float)NT);
    float term = p * logf(p + 1e-8f);
#pragma unroll
    for (int off = 32; off; off >>= 1) term += __shfl_xor(term, off, 64);
    if (e == 0) out[4 * NT] = term;  // out[65536]
  }
}

extern "C" void kernel_launch(void* const* d_in, const int* in_sizes, int n_in,
                              void* d_out, int out_size, void* d_ws, size_t ws_size,
                              hipStream_t stream) {
  const float* x = (const float*)d_in[0];   // [16384, 4096]
  const float* W = (const float*)d_in[1];   // [64, 4096]
  float* out = (float*)d_out;               // scores[32768] | idx[32768] | loss[1]

  unsigned short* Whi = (unsigned short*)d_ws;        // 512 KiB
  unsigned short* Wlo = Whi + (size_t)NE * DM;        // 512 KiB
  float* bsum = (float*)(Wlo + (size_t)NE * DM);      // [1024][64] = 256 KiB

  hipLaunchKernelGGL(w_convert, dim3(128), dim3(256), 0, stream, W, Whi, Wlo);
  hipLaunchKernelGGL(moe_mfma, dim3(NT / MB), dim3(256), 0, stream, x, Whi, Wlo, out, bsum);
  hipLaunchKernelGGL(moe_gate_loss, dim3(1), dim3(256), 0, stream, bsum, out);
}